// Round 1
// baseline (285.823 us; speedup 1.0000x reference)
//
#include <hip/hip_runtime.h>

#define BCNT 16
#define TT 1024
#define DIN 384
#define H1 1024
#define H2 1024
#define KW 9

typedef __attribute__((ext_vector_type(8))) short bhalf8;   // 8 bf16 in 4 VGPRs
typedef __attribute__((ext_vector_type(4))) float f32x4;

typedef const __attribute__((address_space(1))) void* gas_ptr;
typedef __attribute__((address_space(3))) void* lds_ptr;

__device__ __forceinline__ float bf2f(unsigned short u) {
    return __uint_as_float(((unsigned int)u) << 16);
}
__device__ __forceinline__ unsigned short f2bf(float f) {
    unsigned int u = __float_as_uint(f);
    unsigned int r = (u + 0x7FFFu + ((u >> 16) & 1u)) >> 16;  // RNE
    return (unsigned short)r;
}
// mish(x) = x*tanh(log1p(e^x)) = x*(u^2+2u)/(u^2+2u+2), u=e^x (exact algebra)
__device__ __forceinline__ float mish_f(float x) {
    if (x > 20.f) return x;
    float u = __expf(x);
    float n = u * u + 2.f * u;
    return x * n / (n + 2.f);
}

// ---------------- prep kernels ----------------

// fused f32->bf16 cvt for input, w1_w, w2_w + zero sumsq (one launch)
__global__ __launch_bounds__(256) void k_cvt3z(
    const float* __restrict__ s0, unsigned short* __restrict__ d0, int n0,
    const float* __restrict__ s1, unsigned short* __restrict__ d1, int n1,
    const float* __restrict__ s2, unsigned short* __restrict__ d2, int n2,
    float* __restrict__ zb, int n3) {
    int i = blockIdx.x * 256 + threadIdx.x;
    const float* s; unsigned short* d; int j = i;
    if (i < n0) { s = s0; d = d0; }
    else if ((j = i - n0) < n1) { s = s1; d = d1; }
    else if ((j = i - n0 - n1) < n2) { s = s2; d = d2; }
    else if ((j = i - n0 - n1 - n2) < n3) {
        ((float4*)zb)[j] = make_float4(0.f, 0.f, 0.f, 0.f);
        return;
    } else return;
    float4 v = ((const float4*)s)[j];
    ushort4 o;
    o.x = f2bf(v.x); o.y = f2bf(v.y); o.z = f2bf(v.z); o.w = f2bf(v.w);
    ((ushort4*)d)[j] = o;
}

// per-(b,k): norm of d_w over c, then write dwn_s[b,c,k] = d_w/n * d_g * T
__global__ void k_norm_dwn(const float* __restrict__ d_w, const float* __restrict__ d_g,
                           float* __restrict__ dwn_s) {
    int idx = blockIdx.x;           // b*KW + k
    int b = idx / KW, k = idx % KW;
    float s = 0.f;
    for (int c = threadIdx.x; c < H1; c += 256) {
        float v = d_w[((size_t)b * H1 + c) * KW + k];
        s += v * v;
    }
    __shared__ float red[256];
    __shared__ float nsh;
    red[threadIdx.x] = s; __syncthreads();
    for (int st = 128; st > 0; st >>= 1) {
        if (threadIdx.x < st) red[threadIdx.x] += red[threadIdx.x + st];
        __syncthreads();
    }
    if (threadIdx.x == 0) nsh = fmaxf(sqrtf(red[0]), 1e-12f);
    __syncthreads();
    float n = nsh;
    for (int c = threadIdx.x; c < H1; c += 256) {
        size_t o = ((size_t)b * H1 + c) * KW + k;
        dwn_s[o] = d_w[o] / n * d_g[b * H1 + c] * (float)TT;
    }
}

// transpose+scale p_w AND accumulate per-(b,o) sum of squares
__global__ __launch_bounds__(256) void k_tpw2(const float* __restrict__ p_w,
                                              const float* __restrict__ p_g,
                                              unsigned short* __restrict__ pwTu,
                                              float* __restrict__ sumsq) {
    __shared__ float tile[32][33];
    __shared__ float red[8][32];
    int tx = threadIdx.x & 31, ty = threadIdx.x >> 5;  // 32 x 8
    int c0 = blockIdx.x * 32, o0 = blockIdx.y * 32, b = blockIdx.z;
    float s = 0.f;
#pragma unroll
    for (int j = 0; j < 4; j++) {
        float v = p_w[((size_t)b * H1 + c0 + ty + j * 8) * H2 + o0 + tx];
        tile[ty + j * 8][tx] = v;
        s += v * v;
    }
    red[ty][tx] = s;
    __syncthreads();
    if (ty == 0) {
        float t = 0.f;
#pragma unroll
        for (int r = 0; r < 8; r++) t += red[r][tx];
        atomicAdd(&sumsq[(size_t)b * H2 + o0 + tx], t);
    }
#pragma unroll
    for (int j = 0; j < 4; j++) {
        int o = o0 + ty + j * 8, c = c0 + tx;
        float v = tile[tx][ty + j * 8] * p_g[(size_t)b * H1 + c];
        pwTu[((size_t)b * H2 + o) * H1 + c] = f2bf(v);
    }
}

// depthwise conv along T, sliding window; 2 channels per thread (ushort2)
__global__ __launch_bounds__(256) void k_conv(const unsigned short* __restrict__ h,
                                              const float* __restrict__ dwn_s,
                                              const float* __restrict__ d_b,
                                              unsigned short* __restrict__ y) {
    int tid = threadIdx.x;
    int c2 = blockIdx.y * 256 + tid;
    int c = c2 * 2;
    int t0 = blockIdx.x * 64;
    int b = blockIdx.z;
    const ushort2* hb = (const ushort2*)(h + (size_t)b * TT * H1);
    ushort2* yb = (ushort2*)(y + (size_t)b * TT * H1);
    float k0[KW], k1[KW];
#pragma unroll
    for (int i = 0; i < KW; i++) {
        k0[i] = dwn_s[((size_t)b * H1 + c) * KW + i];
        k1[i] = dwn_s[((size_t)b * H1 + c + 1) * KW + i];
    }
    float db0 = d_b[b * H1 + c], db1 = d_b[b * H1 + c + 1];
    float w0[KW], w1[KW];
#pragma unroll
    for (int i = 0; i < 8; i++) {
        int t = t0 - 4 + i;
        if (t >= 0 && t < TT) {
            ushort2 v = hb[(size_t)t * (H1 / 2) + c2];
            w0[i] = bf2f(v.x); w1[i] = bf2f(v.y);
        } else { w0[i] = 0.f; w1[i] = 0.f; }
    }
    for (int j = 0; j < 64; j++) {
        int t = t0 + j;
        int tl = t + 4;
        if (tl < TT) {
            ushort2 v = hb[(size_t)tl * (H1 / 2) + c2];
            w0[8] = bf2f(v.x); w1[8] = bf2f(v.y);
        } else { w0[8] = 0.f; w1[8] = 0.f; }
        float a0 = db0, a1 = db1;
#pragma unroll
        for (int i = 0; i < KW; i++) { a0 += k0[i] * w0[i]; a1 += k1[i] * w1[i]; }
        ushort2 o; o.x = f2bf(a0); o.y = f2bf(a1);
        yb[(size_t)t * (H1 / 2) + c2] = o;
#pragma unroll
        for (int i = 0; i < 8; i++) { w0[i] = w0[i + 1]; w1[i] = w1[i + 1]; }
    }
}

// ------- G1: B-resident streaming GEMM (short-K specialization) -------
// h[m,n] = bf16(mish(sum_k A[m,k]*B[n,k] + bias[n])), A=(16384,384), B=(1024,384).
// B is tiny (0.75 MB): hold a 64-col x 384-K slice in LDS (48 KB), staged ONCE
// (one barrier total); stream A global->VGPR directly in MFMA fragment layout
// (row=l16, k=quad*8+j), so the main loop has NO barriers / NO vmcnt(0) drains —
// this removes the per-k-iter drain that held the staged version at 10% MfmaUtil.
// B LDS layout XOR-swizzled per 16B granule: p=(g&~7)|((g^n)&7) -> ds_read_b128
// lands 2 lanes/bank (free). 512 blocks = 32 M-tiles x 16 N-slices; XCD-swizzled
// so all 16 N-slices of one M-tile (which re-read the same 384 KB A-panel) share
// an XCD's L2. 512 thr, 2 blocks/CU (4 waves/SIMD). Wave = 64 rows x 64 cols.
// K accumulation order (12 sequential 32-k steps) identical to staged version.
__global__ __launch_bounds__(512, 4) void gemm_g1(
    const unsigned short* __restrict__ A, const unsigned short* __restrict__ Bm,
    unsigned short* __restrict__ C, const float* __restrict__ bias) {
    __shared__ __attribute__((aligned(16))) unsigned short Bl[64 * 384];  // 48 KB

    const int tid = threadIdx.x;
    const int lane = tid & 63, wv = tid >> 6;  // 8 waves

    // XCD swizzle: xcd k owns M-tiles [4k,4k+4) x all 16 N-slices (512%8==0: bijective)
    int l = blockIdx.x;
    int xcd = l & 7, s = l >> 3;               // s: 0..63
    int bx = xcd * 4 + (s & 3);                // M-tile 0..31 (512 rows each)
    int by = s >> 2;                           // N-slice 0..15 (64 cols each)
    const int n0 = by * 64;

    // stage B slice once: 64 rows x 48 granules of 16B, swizzled
    for (int i = tid; i < 64 * 48; i += 512) {
        int n = i / 48, g = i % 48;
        bhalf8 v = *(const bhalf8*)&Bm[(size_t)(n0 + n) * DIN + g * 8];
        int p = (g & ~7) | ((g ^ n) & 7);
        *(bhalf8*)&Bl[n * DIN + p * 8] = v;
    }
    __syncthreads();

    const int l16 = lane & 15, quad = lane >> 4;
    const int m0 = bx * 512 + wv * 64;

    f32x4 acc[4][4];
#pragma unroll
    for (int i = 0; i < 4; i++)
#pragma unroll
        for (int j = 0; j < 4; j++)
#pragma unroll
            for (int r = 0; r < 4; r++) acc[i][j][r] = 0.f;

    const unsigned short* Ab = A + (size_t)m0 * DIN + quad * 8;
#pragma unroll
    for (int kk = 0; kk < 12; kk++) {          // 12 x 32-k steps, no barriers
        bhalf8 af[4], bfr[4];
#pragma unroll
        for (int mi = 0; mi < 4; mi++)
            af[mi] = *(const bhalf8*)&Ab[(size_t)(mi * 16 + l16) * DIN + kk * 32];
#pragma unroll
        for (int ni = 0; ni < 4; ni++) {
            int n = ni * 16 + l16;
            int g = kk * 4 + quad;
            int p = (g & ~7) | ((g ^ n) & 7);
            bfr[ni] = *(const bhalf8*)&Bl[n * DIN + p * 8];
        }
#pragma unroll
        for (int mi = 0; mi < 4; mi++)
#pragma unroll
            for (int ni = 0; ni < 4; ni++)
                acc[mi][ni] = __builtin_amdgcn_mfma_f32_16x16x32_bf16(af[mi], bfr[ni],
                                                                     acc[mi][ni], 0, 0, 0);
    }

    // epilogue: D row = quad*4+r, col = l16
#pragma unroll
    for (int mi = 0; mi < 4; mi++)
#pragma unroll
        for (int ni = 0; ni < 4; ni++)
#pragma unroll
            for (int r = 0; r < 4; r++) {
                int gm = m0 + mi * 16 + quad * 4 + r;
                int gn = n0 + ni * 16 + l16;
                float v = mish_f(acc[mi][ni][r] + bias[gn]);
                C[(size_t)gm * H1 + gn] = f2bf(v);
            }
}

// ------- bf16 NT MFMA GEMM: 128 x TN tile, BK=64, 256 threads, 4 blocks/CU -------
// C[m,n] = sum_k A[m,k]*B[n,k], bf16 K-contiguous. BK=64 halves barrier count vs 32.
// LDS rows 64 bf16 = 128 B. Staging chunk = 8 rows (64 lanes x 16 B); lane covers
// (row=lane>>3, slot=lane&7); slot holds global col-group slot^(row&7) [XOR swizzle,
// conflict-free on ds_read_b128: banks 4r%32 distinct, 2-way max].
// TN=128: 4 waves as 2x2, wave=64x64, acc 4x4. TN=64: wave=64x32, acc 4x2.
// MODE 1: C=bf16(v*rsqrt(sumsq[bz*str+n]) + bias[bz*str+n])
// MODE 2: C=f32 (v + bias[n] + bf2f(residbf[idx]))
template <int MODE, int SWIZ, int TN>
__global__ __launch_bounds__(256, 4) void gemm_nt(
    const unsigned short* __restrict__ A, const unsigned short* __restrict__ Bm,
    void* __restrict__ Cp, int Kdim, int lda, int ldb, int ldc,
    long sA, long sB, long sC,
    const float* __restrict__ bias, int biasStride,
    const float* __restrict__ sumsq,
    const unsigned short* __restrict__ residbf) {
    constexpr int WN = TN / 32;                    // B frags per wave (4 or 2)
    __shared__ __attribute__((aligned(16))) unsigned short Al[128 * 64];
    __shared__ __attribute__((aligned(16))) unsigned short Bl[TN * 64];

    const int tid = threadIdx.x;
    const int lane = tid & 63, wv = tid >> 6;      // 4 waves

    int bx, by, bz;
    if constexpr (SWIZ) {
        // G2: 1024 blocks. XCD k owns batches {2k,2k+1}; m-tile fastest.
        int l = blockIdx.x;
        int xcd = l & 7, s = l >> 3;               // s: 0..127
        bz = xcd * 2 + (s >> 6);
        int u = s & 63;
        bx = u & 7; by = u >> 3;
    } else {
        bx = blockIdx.x; by = blockIdx.y; bz = blockIdx.z;
    }
    const int bm = bx * 128, bn = by * TN;

    const unsigned short* Ab = A + (size_t)sA * bz;
    const unsigned short* Bb = Bm + (size_t)sB * bz;

    // staging lane map (XOR swizzle on source column)
    const int rS = lane >> 3;                       // row within 8-row chunk
    const int cS = ((lane & 7) ^ (rS & 7)) * 8;     // global col-group offset (elems)

    const int wm = (wv >> 1) * 64, wn = (wv & 1) * (TN / 2);
    const int l16 = lane & 15, quad = lane >> 4;
    const int fx = l16 & 7;                         // read-side XOR key

    f32x4 acc[4][WN];
#pragma unroll
    for (int i = 0; i < 4; i++)
#pragma unroll
        for (int j = 0; j < WN; j++)
#pragma unroll
            for (int r = 0; r < 4; r++) acc[i][j][r] = 0.f;

    const int ktiles = Kdim / 64;
    for (int kt = 0; kt < ktiles; ++kt) {
        const int kofs = kt * 64 + cS;
        // A: 16 chunks of 8 rows, 4 per wave
#pragma unroll
        for (int i = 0; i < 4; i++) {
            const int ch = i * 4 + wv;
            const unsigned short* ga = Ab + (size_t)(bm + ch * 8 + rS) * lda + kofs;
            __builtin_amdgcn_global_load_lds((gas_ptr)ga, (lds_ptr)&Al[ch * 512], 16, 0, 0);
        }
        // B: TN/8 chunks, TN/32 per wave
#pragma unroll
        for (int i = 0; i < TN / 32; i++) {
            const int ch = i * 4 + wv;
            const unsigned short* gb = Bb + (size_t)(bn + ch * 8 + rS) * ldb + kofs;
            __builtin_amdgcn_global_load_lds((gas_ptr)gb, (lds_ptr)&Bl[ch * 512], 16, 0, 0);
        }
        __syncthreads();

#pragma unroll
        for (int kk = 0; kk < 2; kk++) {
            const int cg = ((kk * 4 + quad) ^ fx) * 8;   // swizzled col offset
            bhalf8 af[4], bf[WN];
#pragma unroll
            for (int mi = 0; mi < 4; mi++)
                af[mi] = *(const bhalf8*)&Al[(wm + mi * 16 + l16) * 64 + cg];
#pragma unroll
            for (int ni = 0; ni < WN; ni++)
                bf[ni] = *(const bhalf8*)&Bl[(wn + ni * 16 + l16) * 64 + cg];
#pragma unroll
            for (int mi = 0; mi < 4; mi++)
#pragma unroll
                for (int ni = 0; ni < WN; ni++)
                    acc[mi][ni] = __builtin_amdgcn_mfma_f32_16x16x32_bf16(af[mi], bf[ni],
                                                                         acc[mi][ni], 0, 0, 0);
        }
        __syncthreads();
    }

    // epilogue: D row = quad*4+r, col = lane&15
#pragma unroll
    for (int mi = 0; mi < 4; mi++)
#pragma unroll
        for (int ni = 0; ni < WN; ni++)
#pragma unroll
            for (int r = 0; r < 4; r++) {
                int gm = bm + wm + mi * 16 + quad * 4 + r;
                int gn = bn + wn + ni * 16 + l16;
                float v = acc[mi][ni][r];
                size_t cidx = (size_t)sC * bz + (size_t)gm * ldc + gn;
                if constexpr (MODE == 0) {
                    v = mish_f(v + bias[gn]);
                    ((unsigned short*)Cp)[cidx] = f2bf(v);
                } else if constexpr (MODE == 1) {
                    size_t si = (size_t)bz * biasStride + gn;
                    float rr = rsqrtf(fmaxf(sumsq[si], 1e-24f));
                    v = v * rr + bias[si];
                    ((unsigned short*)Cp)[cidx] = f2bf(v);
                } else {
                    v += bias[gn] + bf2f(residbf[cidx]);
                    ((float*)Cp)[cidx] = v;
                }
            }
}

// ---------------- launch ----------------

extern "C" void kernel_launch(void* const* d_in, const int* in_sizes, int n_in,
                              void* d_out, int out_size, void* d_ws, size_t ws_size,
                              hipStream_t stream) {
    const float* input = (const float*)d_in[0];
    const float* d_w   = (const float*)d_in[1];
    const float* d_g   = (const float*)d_in[2];
    const float* d_b   = (const float*)d_in[3];
    const float* p_w   = (const float*)d_in[4];
    const float* p_g   = (const float*)d_in[5];
    const float* p_b   = (const float*)d_in[6];
    const float* w1_w  = (const float*)d_in[7];
    const float* w1_b  = (const float*)d_in[8];
    const float* w2_w  = (const float*)d_in[9];
    const float* w2_b  = (const float*)d_in[10];
    float* out = (float*)d_out;

    char* ws = (char*)d_ws;
    size_t off = 0;
    auto alloc = [&](size_t bytes) {
        char* p = ws + off;
        off += (bytes + 255) & ~(size_t)255;
        return p;
    };
    float* dwn_s         = (float*)alloc((size_t)BCNT * H1 * KW * 4);
    float* sumsq         = (float*)alloc((size_t)BCNT * H2 * 4);
    unsigned short* inbf = (unsigned short*)alloc((size_t)BCNT * TT * DIN * 2);
    unsigned short* w1bf = (unsigned short*)alloc((size_t)H1 * DIN * 2);
    unsigned short* w2bf = (unsigned short*)alloc((size_t)DIN * H2 * 2);
    unsigned short* h    = (unsigned short*)alloc((size_t)BCNT * TT * H1 * 2);
    unsigned short* y    = (unsigned short*)alloc((size_t)BCNT * TT * H1 * 2);
    unsigned short* pwTu = (unsigned short*)alloc((size_t)BCNT * H2 * H1 * 2);
    unsigned short* zt   = (unsigned short*)alloc((size_t)BCNT * TT * H2 * 2);

    // f32 -> bf16 conversions + zero sumsq (one launch)
    const int n4_in = BCNT * TT * DIN / 4, n4_w1 = H1 * DIN / 4, n4_w2 = DIN * H2 / 4;
    const int n4_z = BCNT * H2 / 4;
    k_cvt3z<<<(n4_in + n4_w1 + n4_w2 + n4_z + 255) / 256, 256, 0, stream>>>(
        input, inbf, n4_in, w1_w, w1bf, n4_w1, w2_w, w2bf, n4_w2, sumsq, n4_z);

    // weight prep
    k_norm_dwn<<<BCNT * KW, 256, 0, stream>>>(d_w, d_g, dwn_s);
    k_tpw2<<<dim3(H1 / 32, H2 / 32, BCNT), 256, 0, stream>>>(p_w, p_g, pwTu, sumsq);

    // G1: h = bf16(mish(input @ w1_w^T + w1_b)) — B-resident streaming GEMM,
    // 512 blocks (32 M-tiles x 16 N-slices, XCD-swizzled), no main-loop barriers
    gemm_g1<<<512, 512, 0, stream>>>(inbf, w1bf, h, w1_b);

    // depthwise conv -> y (B*T, H1) bf16
    k_conv<<<dim3(TT / 64, H1 / 512, BCNT), 256, 0, stream>>>(h, dwn_s, d_b, y);

    // G2 (batched, XCD-swizzled, 1024 blocks): zt = rsqrt(sumsq)*(y.pwTu) + p_b
    gemm_nt<1, 1, 128><<<dim3(1024, 1, 1), 256, 0, stream>>>(
        y, pwTu, zt, H1, H1, H1, H2, (long)TT * H1, (long)H2 * H1, (long)TT * H2,
        p_b, H2, sumsq, nullptr);

    // G3: out = zt @ w2^T + w2_b + resid; 128x64 tiles -> 768 blocks
    gemm_nt<2, 0, 64><<<dim3(BCNT * TT / 128, DIN / 64, 1), 256, 0, stream>>>(
        zt, w2bf, out, H2, H2, H2, DIN, 0, 0, 0, w2_b, 0, nullptr, inbf);
}

// Round 2
// 280.685 us; speedup vs baseline: 1.0183x; 1.0183x over previous
//
#include <hip/hip_runtime.h>

#define BCNT 16
#define TT 1024
#define DIN 384
#define H1 1024
#define H2 1024
#define KW 9

typedef __attribute__((ext_vector_type(8))) short bhalf8;   // 8 bf16 in 4 VGPRs
typedef __attribute__((ext_vector_type(4))) float f32x4;

typedef const __attribute__((address_space(1))) void* gas_ptr;
typedef __attribute__((address_space(3))) void* lds_ptr;

__device__ __forceinline__ float bf2f(unsigned short u) {
    return __uint_as_float(((unsigned int)u) << 16);
}
__device__ __forceinline__ unsigned short f2bf(float f) {
    unsigned int u = __float_as_uint(f);
    unsigned int r = (u + 0x7FFFu + ((u >> 16) & 1u)) >> 16;  // RNE
    return (unsigned short)r;
}
// mish(x) = x*tanh(log1p(e^x)) = x*(u^2+2u)/(u^2+2u+2), u=e^x (exact algebra)
__device__ __forceinline__ float mish_f(float x) {
    if (x > 20.f) return x;
    float u = __expf(x);
    float n = u * u + 2.f * u;
    return x * n / (n + 2.f);
}

// ---------------- prep kernels ----------------

// fused f32->bf16 cvt for input, w1_w, w2_w + zero sumsq (one launch)
__global__ __launch_bounds__(256) void k_cvt3z(
    const float* __restrict__ s0, unsigned short* __restrict__ d0, int n0,
    const float* __restrict__ s1, unsigned short* __restrict__ d1, int n1,
    const float* __restrict__ s2, unsigned short* __restrict__ d2, int n2,
    float* __restrict__ zb, int n3) {
    int i = blockIdx.x * 256 + threadIdx.x;
    const float* s; unsigned short* d; int j = i;
    if (i < n0) { s = s0; d = d0; }
    else if ((j = i - n0) < n1) { s = s1; d = d1; }
    else if ((j = i - n0 - n1) < n2) { s = s2; d = d2; }
    else if ((j = i - n0 - n1 - n2) < n3) {
        ((float4*)zb)[j] = make_float4(0.f, 0.f, 0.f, 0.f);
        return;
    } else return;
    float4 v = ((const float4*)s)[j];
    ushort4 o;
    o.x = f2bf(v.x); o.y = f2bf(v.y); o.z = f2bf(v.z); o.w = f2bf(v.w);
    ((ushort4*)d)[j] = o;
}

// per-(b,k): norm of d_w over c, then write dwn_s[b,c,k] = d_w/n * d_g * T
__global__ void k_norm_dwn(const float* __restrict__ d_w, const float* __restrict__ d_g,
                           float* __restrict__ dwn_s) {
    int idx = blockIdx.x;           // b*KW + k
    int b = idx / KW, k = idx % KW;
    float s = 0.f;
    for (int c = threadIdx.x; c < H1; c += 256) {
        float v = d_w[((size_t)b * H1 + c) * KW + k];
        s += v * v;
    }
    __shared__ float red[256];
    __shared__ float nsh;
    red[threadIdx.x] = s; __syncthreads();
    for (int st = 128; st > 0; st >>= 1) {
        if (threadIdx.x < st) red[threadIdx.x] += red[threadIdx.x + st];
        __syncthreads();
    }
    if (threadIdx.x == 0) nsh = fmaxf(sqrtf(red[0]), 1e-12f);
    __syncthreads();
    float n = nsh;
    for (int c = threadIdx.x; c < H1; c += 256) {
        size_t o = ((size_t)b * H1 + c) * KW + k;
        dwn_s[o] = d_w[o] / n * d_g[b * H1 + c] * (float)TT;
    }
}

// transpose+scale p_w AND accumulate per-(b,o) sum of squares
__global__ __launch_bounds__(256) void k_tpw2(const float* __restrict__ p_w,
                                              const float* __restrict__ p_g,
                                              unsigned short* __restrict__ pwTu,
                                              float* __restrict__ sumsq) {
    __shared__ float tile[32][33];
    __shared__ float red[8][32];
    int tx = threadIdx.x & 31, ty = threadIdx.x >> 5;  // 32 x 8
    int c0 = blockIdx.x * 32, o0 = blockIdx.y * 32, b = blockIdx.z;
    float s = 0.f;
#pragma unroll
    for (int j = 0; j < 4; j++) {
        float v = p_w[((size_t)b * H1 + c0 + ty + j * 8) * H2 + o0 + tx];
        tile[ty + j * 8][tx] = v;
        s += v * v;
    }
    red[ty][tx] = s;
    __syncthreads();
    if (ty == 0) {
        float t = 0.f;
#pragma unroll
        for (int r = 0; r < 8; r++) t += red[r][tx];
        atomicAdd(&sumsq[(size_t)b * H2 + o0 + tx], t);
    }
#pragma unroll
    for (int j = 0; j < 4; j++) {
        int o = o0 + ty + j * 8, c = c0 + tx;
        float v = tile[tx][ty + j * 8] * p_g[(size_t)b * H1 + c];
        pwTu[((size_t)b * H2 + o) * H1 + c] = f2bf(v);
    }
}

// depthwise conv along T, sliding window; 2 channels per thread (ushort2)
__global__ __launch_bounds__(256) void k_conv(const unsigned short* __restrict__ h,
                                              const float* __restrict__ dwn_s,
                                              const float* __restrict__ d_b,
                                              unsigned short* __restrict__ y) {
    int tid = threadIdx.x;
    int c2 = blockIdx.y * 256 + tid;
    int c = c2 * 2;
    int t0 = blockIdx.x * 64;
    int b = blockIdx.z;
    const ushort2* hb = (const ushort2*)(h + (size_t)b * TT * H1);
    ushort2* yb = (ushort2*)(y + (size_t)b * TT * H1);
    float k0[KW], k1[KW];
#pragma unroll
    for (int i = 0; i < KW; i++) {
        k0[i] = dwn_s[((size_t)b * H1 + c) * KW + i];
        k1[i] = dwn_s[((size_t)b * H1 + c + 1) * KW + i];
    }
    float db0 = d_b[b * H1 + c], db1 = d_b[b * H1 + c + 1];
    float w0[KW], w1[KW];
#pragma unroll
    for (int i = 0; i < 8; i++) {
        int t = t0 - 4 + i;
        if (t >= 0 && t < TT) {
            ushort2 v = hb[(size_t)t * (H1 / 2) + c2];
            w0[i] = bf2f(v.x); w1[i] = bf2f(v.y);
        } else { w0[i] = 0.f; w1[i] = 0.f; }
    }
    for (int j = 0; j < 64; j++) {
        int t = t0 + j;
        int tl = t + 4;
        if (tl < TT) {
            ushort2 v = hb[(size_t)tl * (H1 / 2) + c2];
            w0[8] = bf2f(v.x); w1[8] = bf2f(v.y);
        } else { w0[8] = 0.f; w1[8] = 0.f; }
        float a0 = db0, a1 = db1;
#pragma unroll
        for (int i = 0; i < KW; i++) { a0 += k0[i] * w0[i]; a1 += k1[i] * w1[i]; }
        ushort2 o; o.x = f2bf(a0); o.y = f2bf(a1);
        yb[(size_t)t * (H1 / 2) + c2] = o;
#pragma unroll
        for (int i = 0; i < 8; i++) { w0[i] = w0[i + 1]; w1[i] = w1[i + 1]; }
    }
}

// ------- bf16 NT MFMA GEMM: 128 x TN tile, BK=64, 256 threads -------
// C[m,n] = sum_k A[m,k]*B[n,k], bf16 K-contiguous.
// T3+T4 (m218/m248): double-buffered LDS + COUNTED vmcnt. Loads for tile t+1 are
// issued before compute(t) and stay in flight across both barriers; the main loop
// never drains vmcnt to 0 (the old stage->syncthreads->compute structure exposed
// full load latency every K-tile; G1-K=384 and G2-K=1024 both sat at ~44us because
// of it). Raw s_barrier (NOT __syncthreads -- that emits vmcnt(0)).
// vmcnt(N): N = loads/tile/thread = A(4) + B(TN/32) -> 8 (TN=128) or 6 (TN=64).
// lgkmcnt(0)+sched_barrier before 2nd barrier: my ds_reads have completed before
// any wave may overwrite this buffer next iteration (rule #18 insurance).
// LDS: 2 x (128+TN) x 64 x 2B = 64KB (TN=128, 2 blk/CU) or 48KB (TN=64, 3 blk/CU).
// XOR swizzle as before: staging slot (lane&7)^(row&7); read cg=((kk*4+quad)^fx)*8
// -> conflict-free ds_read_b128 (counter showed 0).
// MODE 0: C=bf16(mish(v + bias[n]))
// MODE 1: C=bf16(v*rsqrt(sumsq[bz*str+n]) + bias[bz*str+n])
// MODE 2: C=f32 (v + bias[n] + bf2f(residbf[idx]))
template <int MODE, int SWIZ, int TN>
__global__ __launch_bounds__(256, TN == 128 ? 2 : 3) void gemm_nt(
    const unsigned short* __restrict__ A, const unsigned short* __restrict__ Bm,
    void* __restrict__ Cp, int Kdim, int lda, int ldb, int ldc,
    long sA, long sB, long sC,
    const float* __restrict__ bias, int biasStride,
    const float* __restrict__ sumsq,
    const unsigned short* __restrict__ residbf) {
    constexpr int WN = TN / 32;                    // B frags per wave (4 or 2)
    __shared__ __attribute__((aligned(16))) unsigned short Al[2][128 * 64];
    __shared__ __attribute__((aligned(16))) unsigned short Bl[2][TN * 64];

    const int tid = threadIdx.x;
    const int lane = tid & 63, wv = tid >> 6;      // 4 waves

    int bx, by, bz;
    if constexpr (SWIZ) {
        // G2: 1024 blocks. XCD k owns batches {2k,2k+1}; m-tile fastest.
        int l = blockIdx.x;
        int xcd = l & 7, s = l >> 3;               // s: 0..127
        bz = xcd * 2 + (s >> 6);
        int u = s & 63;
        bx = u & 7; by = u >> 3;
    } else {
        bx = blockIdx.x; by = blockIdx.y; bz = blockIdx.z;
    }
    const int bm = bx * 128, bn = by * TN;

    const unsigned short* Ab = A + (size_t)sA * bz;
    const unsigned short* Bb = Bm + (size_t)sB * bz;

    // staging lane map (XOR swizzle on source column)
    const int rS = lane >> 3;                       // row within 8-row chunk
    const int cS = ((lane & 7) ^ (rS & 7)) * 8;     // global col-group offset (elems)

    const int wm = (wv >> 1) * 64, wn = (wv & 1) * (TN / 2);
    const int l16 = lane & 15, quad = lane >> 4;
    const int fx = l16 & 7;                         // read-side XOR key

    f32x4 acc[4][WN];
#pragma unroll
    for (int i = 0; i < 4; i++)
#pragma unroll
        for (int j = 0; j < WN; j++)
#pragma unroll
            for (int r = 0; r < 4; r++) acc[i][j][r] = 0.f;

    // stage one K-tile into buffer `buf` (A: 4 loads, B: TN/32 loads per thread)
    auto STAGE = [&](int kt, int buf) {
        const int kofs = kt * 64 + cS;
#pragma unroll
        for (int i = 0; i < 4; i++) {
            const int ch = i * 4 + wv;
            const unsigned short* ga = Ab + (size_t)(bm + ch * 8 + rS) * lda + kofs;
            __builtin_amdgcn_global_load_lds((gas_ptr)ga, (lds_ptr)&Al[buf][ch * 512], 16, 0, 0);
        }
#pragma unroll
        for (int i = 0; i < TN / 32; i++) {
            const int ch = i * 4 + wv;
            const unsigned short* gb = Bb + (size_t)(bn + ch * 8 + rS) * ldb + kofs;
            __builtin_amdgcn_global_load_lds((gas_ptr)gb, (lds_ptr)&Bl[buf][ch * 512], 16, 0, 0);
        }
    };

    const int ktiles = Kdim / 64;
    int cur = 0;
    STAGE(0, 0);                                    // prologue: tile 0 in flight

    for (int kt = 0; kt < ktiles; ++kt) {
        if (kt + 1 < ktiles) {
            STAGE(kt + 1, cur ^ 1);                 // next tile: stays in flight
            if constexpr (TN == 128)
                asm volatile("s_waitcnt vmcnt(8)" ::: "memory");   // tile kt landed
            else
                asm volatile("s_waitcnt vmcnt(6)" ::: "memory");
        } else {
            asm volatile("s_waitcnt vmcnt(0)" ::: "memory");
        }
        __builtin_amdgcn_s_barrier();               // tile kt visible to all waves

#pragma unroll
        for (int kk = 0; kk < 2; kk++) {
            const int cg = ((kk * 4 + quad) ^ fx) * 8;   // swizzled col offset
            bhalf8 af[4], bf[WN];
#pragma unroll
            for (int mi = 0; mi < 4; mi++)
                af[mi] = *(const bhalf8*)&Al[cur][(wm + mi * 16 + l16) * 64 + cg];
#pragma unroll
            for (int ni = 0; ni < WN; ni++)
                bf[ni] = *(const bhalf8*)&Bl[cur][(wn + ni * 16 + l16) * 64 + cg];
            __builtin_amdgcn_s_setprio(1);
#pragma unroll
            for (int mi = 0; mi < 4; mi++)
#pragma unroll
                for (int ni = 0; ni < WN; ni++)
                    acc[mi][ni] = __builtin_amdgcn_mfma_f32_16x16x32_bf16(af[mi], bf[ni],
                                                                         acc[mi][ni], 0, 0, 0);
            __builtin_amdgcn_s_setprio(0);
        }
        // my ds_reads of buf[cur] have fully completed before I pass the barrier;
        // after it, other waves may begin overwriting buf[cur] via STAGE.
        asm volatile("s_waitcnt lgkmcnt(0)" ::: "memory");
        __builtin_amdgcn_sched_barrier(0);
        __builtin_amdgcn_s_barrier();
        cur ^= 1;
    }

    // epilogue: D row = quad*4+r, col = lane&15
#pragma unroll
    for (int mi = 0; mi < 4; mi++)
#pragma unroll
        for (int ni = 0; ni < WN; ni++)
#pragma unroll
            for (int r = 0; r < 4; r++) {
                int gm = bm + wm + mi * 16 + quad * 4 + r;
                int gn = bn + wn + ni * 16 + l16;
                float v = acc[mi][ni][r];
                size_t cidx = (size_t)sC * bz + (size_t)gm * ldc + gn;
                if constexpr (MODE == 0) {
                    v = mish_f(v + bias[gn]);
                    ((unsigned short*)Cp)[cidx] = f2bf(v);
                } else if constexpr (MODE == 1) {
                    size_t si = (size_t)bz * biasStride + gn;
                    float rr = rsqrtf(fmaxf(sumsq[si], 1e-24f));
                    v = v * rr + bias[si];
                    ((unsigned short*)Cp)[cidx] = f2bf(v);
                } else {
                    v += bias[gn] + bf2f(residbf[cidx]);
                    ((float*)Cp)[cidx] = v;
                }
            }
}

// ---------------- launch ----------------

extern "C" void kernel_launch(void* const* d_in, const int* in_sizes, int n_in,
                              void* d_out, int out_size, void* d_ws, size_t ws_size,
                              hipStream_t stream) {
    const float* input = (const float*)d_in[0];
    const float* d_w   = (const float*)d_in[1];
    const float* d_g   = (const float*)d_in[2];
    const float* d_b   = (const float*)d_in[3];
    const float* p_w   = (const float*)d_in[4];
    const float* p_g   = (const float*)d_in[5];
    const float* p_b   = (const float*)d_in[6];
    const float* w1_w  = (const float*)d_in[7];
    const float* w1_b  = (const float*)d_in[8];
    const float* w2_w  = (const float*)d_in[9];
    const float* w2_b  = (const float*)d_in[10];
    float* out = (float*)d_out;

    char* ws = (char*)d_ws;
    size_t off = 0;
    auto alloc = [&](size_t bytes) {
        char* p = ws + off;
        off += (bytes + 255) & ~(size_t)255;
        return p;
    };
    float* dwn_s         = (float*)alloc((size_t)BCNT * H1 * KW * 4);
    float* sumsq         = (float*)alloc((size_t)BCNT * H2 * 4);
    unsigned short* inbf = (unsigned short*)alloc((size_t)BCNT * TT * DIN * 2);
    unsigned short* w1bf = (unsigned short*)alloc((size_t)H1 * DIN * 2);
    unsigned short* w2bf = (unsigned short*)alloc((size_t)DIN * H2 * 2);
    unsigned short* h    = (unsigned short*)alloc((size_t)BCNT * TT * H1 * 2);
    unsigned short* y    = (unsigned short*)alloc((size_t)BCNT * TT * H1 * 2);
    unsigned short* pwTu = (unsigned short*)alloc((size_t)BCNT * H2 * H1 * 2);
    unsigned short* zt   = (unsigned short*)alloc((size_t)BCNT * TT * H2 * 2);

    // f32 -> bf16 conversions + zero sumsq (one launch)
    const int n4_in = BCNT * TT * DIN / 4, n4_w1 = H1 * DIN / 4, n4_w2 = DIN * H2 / 4;
    const int n4_z = BCNT * H2 / 4;
    k_cvt3z<<<(n4_in + n4_w1 + n4_w2 + n4_z + 255) / 256, 256, 0, stream>>>(
        input, inbf, n4_in, w1_w, w1bf, n4_w1, w2_w, w2bf, n4_w2, sumsq, n4_z);

    // weight prep
    k_norm_dwn<<<BCNT * KW, 256, 0, stream>>>(d_w, d_g, dwn_s);
    k_tpw2<<<dim3(H1 / 32, H2 / 32, BCNT), 256, 0, stream>>>(p_w, p_g, pwTu, sumsq);

    // G1: h = bf16(mish(input @ w1_w^T + w1_b)), (B*T, H1); 1024 blocks, 6 K-tiles
    gemm_nt<0, 0, 128><<<dim3(BCNT * TT / 128, H1 / 128, 1), 256, 0, stream>>>(
        inbf, w1bf, h, DIN, DIN, DIN, H1, 0, 0, 0, w1_b, 0, nullptr, nullptr);

    // depthwise conv -> y (B*T, H1) bf16
    k_conv<<<dim3(TT / 64, H1 / 512, BCNT), 256, 0, stream>>>(h, dwn_s, d_b, y);

    // G2 (batched, XCD-swizzled, 1024 blocks): zt = rsqrt(sumsq)*(y.pwTu) + p_b
    gemm_nt<1, 1, 128><<<dim3(1024, 1, 1), 256, 0, stream>>>(
        y, pwTu, zt, H1, H1, H1, H2, (long)TT * H1, (long)H2 * H1, (long)TT * H2,
        p_b, H2, sumsq, nullptr);

    // G3: out = zt @ w2^T + w2_b + resid; 128x64 tiles -> 768 blocks
    gemm_nt<2, 0, 64><<<dim3(BCNT * TT / 128, DIN / 64, 1), 256, 0, stream>>>(
        zt, w2bf, out, H2, H2, H2, DIN, 0, 0, 0, w2_b, 0, nullptr, inbf);
}